// Round 9
// baseline (168.750 us; speedup 1.0000x reference)
//
#include <hip/hip_runtime.h>

#define NEGSLOPE 0.2f
#define NINF (-3.4e38f)

typedef _Float16 half8 __attribute__((ext_vector_type(8)));
typedef _Float16 half2v __attribute__((ext_vector_type(2)));
typedef float f32x4 __attribute__((ext_vector_type(4)));
typedef unsigned long long u64;

#define YSTRIDE 72  // f16 units; row stride 144 B (16B-aligned for b128)

// ---------------------------------------------------------------------------
// topk v7: TWO rows per wave (shared candidate loads, 2 interleaved
// extraction chains for ILP on the serial DPP/readlane latency).
// key = bits(||xj-xn||^2); MIN-select of (key<<32)|j -> tie = smaller j
// (matches jax). Per-lane top-2 cache per row; self-skip; zmask + rare
// refill. Wave argmin = 6-step DPP min chain (old=-1 neutral) ->
// lane 63, then ballot/ffs/readlane decode (R7-proven structure).
// Blocks >= 2048 do the W1 -> w1g f16 fragment transpose (folded dispatch).
// ---------------------------------------------------------------------------
template <int CTRL>
__device__ __forceinline__ unsigned dpp_movm(unsigned v) {
    return (unsigned)__builtin_amdgcn_update_dpp(-1, (int)v, CTRL, 0xF, 0xF, false);
}

__global__ __launch_bounds__(256) void topk_kernel(const float* __restrict__ x,
                                                   int* __restrict__ idx_out,
                                                   const float* __restrict__ w1,
                                                   _Float16* __restrict__ w1g) {
    if (blockIdx.x >= 2048) {
        // ---- weight-prep path (8 blocks x 256 threads x 12 elems) ----
        int tid = (blockIdx.x - 2048) * 256 + threadIdx.x;
#pragma unroll
        for (int it = 0; it < 12; ++it, tid += 2048) {
            int j = tid & 7;
            int L = (tid >> 3) & 63;
            int r = tid >> 9;          // r = ks*4 + t4
            int t4 = r & 3;
            int ks = r >> 2;
            int q = L >> 4, c = L & 15;
            int i = ks >> 1;
            int o = 32 * (ks & 1) + 8 * q + j;
            int u = 16 * t4 + c;
            w1g[tid] = (_Float16)w1[(u * 6 + i) * 64 + o];
        }
        return;
    }

    const int wave = threadIdx.x >> 6;
    const int lane = threadIdx.x & 63;
    const int rbase = blockIdx.x * 8 + wave * 2;   // rows rbase, rbase+1
    const int b = rbase >> 11;                     // same batch for both
    const int nA = rbase & 2047;
    const int nB = nA + 1;
    const float* xb = x + b * 6144;
    const float xa0 = xb[nA], xa1 = xb[2048 + nA], xa2 = xb[4096 + nA];
    const float xb0 = xb[nB], xb1 = xb[2048 + nB], xb2 = xb[4096 + nB];

    unsigned skA[32], skB[32];
    u64 g1A = ~0ull, g2A = ~0ull, g1B = ~0ull, g2B = ~0ull;

#pragma unroll
    for (int t = 0; t < 32; ++t) {
        const int j = t * 64 + lane;
        const float c0 = xb[j];
        const float c1 = xb[2048 + j];
        const float c2 = xb[4096 + j];
        // row A
        {
            const float dx = c0 - xa0, dy = c1 - xa1, dz = c2 - xa2;
            const float d = dx * dx + dy * dy + dz * dz;
            const unsigned s = __float_as_uint(d);
            skA[t] = s;
            const u64 cand = ((u64)s << 32) | (unsigned)j;
            const bool lt = cand < g1A;
            const u64 dem = lt ? g1A : cand;
            g1A = lt ? cand : g1A;
            if (dem < g2A) g2A = dem;
        }
        // row B
        {
            const float dx = c0 - xb0, dy = c1 - xb1, dz = c2 - xb2;
            const float d = dx * dx + dy * dy + dz * dz;
            const unsigned s = __float_as_uint(d);
            skB[t] = s;
            const u64 cand = ((u64)s << 32) | (unsigned)j;
            const bool lt = cand < g1B;
            const u64 dem = lt ? g1B : cand;
            g1B = lt ? cand : g1B;
            if (dem < g2B) g2B = dem;
        }
    }

    const int obA = rbase * 20;
    const int obB = obA + 20;

    // self-skip: d(self)=0 is the strict global min of each row.
    if (lane == 0) { idx_out[obA] = nA; idx_out[obB] = nB; }
    {
        const bool sA = (lane == (nA & 63));
        const bool sB = (lane == (nB & 63));
        if (sA) { g1A = g2A; g2A = ~0ull; }
        if (sB) { g1B = g2B; g2B = ~0ull; }
    }
    unsigned zmA = (lane == (nA & 63)) ? (1u << (nA >> 6)) : 0u;
    unsigned zmB = (lane == (nB & 63)) ? (1u << (nB >> 6)) : 0u;

#define DPPMIN(mv)                                                         \
    { unsigned o = dpp_movm<0x111>(mv); mv = o < mv ? o : mv; }            \
    { unsigned o = dpp_movm<0x112>(mv); mv = o < mv ? o : mv; }            \
    { unsigned o = dpp_movm<0x114>(mv); mv = o < mv ? o : mv; }            \
    { unsigned o = dpp_movm<0x118>(mv); mv = o < mv ? o : mv; }            \
    { unsigned o = dpp_movm<0x142>(mv); mv = o < mv ? o : mv; }            \
    { unsigned o = dpp_movm<0x143>(mv); mv = o < mv ? o : mv; }

#define REFILL(SK, ZM, G1, G2)                                             \
    {                                                                      \
        u64 n1 = ~0ull, n2 = ~0ull;                                        \
        _Pragma("unroll") for (int t = 0; t < 32; ++t) {                   \
            const unsigned sv = ((ZM >> t) & 1u) ? 0xFFFFFFFFu : SK[t];    \
            const u64 cc = ((u64)sv << 32) | (unsigned)(t * 64 + lane);    \
            const bool lt = cc < n1;                                       \
            const u64 dem = lt ? n1 : cc;                                  \
            n1 = lt ? cc : n1;                                             \
            if (dem < n2) n2 = dem;                                        \
        }                                                                  \
        G1 = n1;                                                           \
        G2 = n2;                                                           \
    }

    for (int k = 1; k < 20; ++k) {
        // two independent argmin chains, interleaved for ILP
        unsigned mA = (unsigned)(g1A >> 32);
        unsigned mB = (unsigned)(g1B >> 32);
        DPPMIN(mA)
        DPPMIN(mB)
        const unsigned KA = (unsigned)__builtin_amdgcn_readlane((int)mA, 63);
        const unsigned KB = (unsigned)__builtin_amdgcn_readlane((int)mB, 63);
        const u64 ballA = __ballot((unsigned)(g1A >> 32) == KA);
        const u64 ballB = __ballot((unsigned)(g1B >> 32) == KB);
        const int LsA = __ffsll(ballA) - 1;
        const int LsB = __ffsll(ballB) - 1;
        const int bjA = __builtin_amdgcn_readlane((int)(unsigned)g1A, LsA);
        const int bjB = __builtin_amdgcn_readlane((int)(unsigned)g1B, LsB);
        if (lane == 0) {
            idx_out[obA + k] = bjA;
            idx_out[obB + k] = bjB;
        }

        if (k < 19) {
            const bool iA = (lane == LsA);
            zmA |= iA ? (1u << (bjA >> 6)) : 0u;
            if (iA) { g1A = g2A; g2A = ~0ull; }
            const bool iB = (lane == LsB);
            zmB |= iB ? (1u << (bjB >> 6)) : 0u;
            if (iB) { g1B = g2B; g2B = ~0ull; }
            const unsigned h1A = (unsigned)(g1A >> 32);
            const unsigned h1B = (unsigned)(g1B >> 32);
            if (__builtin_amdgcn_readlane((int)h1A, LsA) == -1)
                REFILL(skA, zmA, g1A, g2A)
            if (__builtin_amdgcn_readlane((int)h1B, LsB) == -1)
                REFILL(skB, zmB, g1B, g2B)
        }
    }
#undef REFILL
#undef DPPMIN
}

// ---------------------------------------------------------------------------
// mlp via single K=384 MFMA GEMM (FROZEN from R8 for clean attribution):
// XOR-swizzled y tile, paired b32 LDS stores, swizzled ds_read_b128 A-frags.
// ---------------------------------------------------------------------------
__global__ __launch_bounds__(128, 2) void mlp_mfma(
    const float* __restrict__ x, const int* __restrict__ idx,
    const float* __restrict__ w0, const float* __restrict__ bn0s,
    const float* __restrict__ bn0b, const _Float16* __restrict__ w1g,
    const float* __restrict__ bn1s, const float* __restrict__ bn1b,
    const float* __restrict__ wc, const float* __restrict__ bncs,
    const float* __restrict__ bncb, float* __restrict__ out) {
    __shared__ __align__(16) _Float16 yL[2][80 * YSTRIDE];
    __shared__ __align__(4) _Float16 ehL[2][6][80];
    const int wave = threadIdx.x >> 6;
    const int lane = threadIdx.x & 63;
    const int q = lane >> 4, c = lane & 15;
    const int gw = blockIdx.x * 2 + wave;     // 0..4095
    const int b = gw >> 9;                    // 512 waves per batch
    const int P0 = (gw & 511) * 4;
    const float* xb = x + b * 6144;
    _Float16* yw = yL[wave];
    _Float16(*ehw)[80] = ehL[wave];

    // ---- e-stage ----
    float e0[6], e1_[6];
    {
        const int k = lane >> 2, pt = lane & 3;
        const int n = P0 + pt;
        const int j = idx[(b * 2048 + n) * 20 + k];
        const float c0 = xb[n], c1 = xb[2048 + n], c2 = xb[4096 + n];
        e0[0] = xb[j] - c0; e0[1] = xb[2048 + j] - c1; e0[2] = xb[4096 + j] - c2;
        e0[3] = c0; e0[4] = c1; e0[5] = c2;
#pragma unroll
        for (int i = 0; i < 6; ++i) ehw[i][lane] = (_Float16)e0[i];
    }
#pragma unroll
    for (int i = 0; i < 6; ++i) e1_[i] = 0.f;
    if (lane < 16) {
        const int el = 64 + lane;
        const int k = el >> 2, pt = el & 3;
        const int n = P0 + pt;
        const int j = idx[(b * 2048 + n) * 20 + k];
        const float c0 = xb[n], c1 = xb[2048 + n], c2 = xb[4096 + n];
        e1_[0] = xb[j] - c0; e1_[1] = xb[2048 + j] - c1; e1_[2] = xb[4096 + j] - c2;
        e1_[3] = c0; e1_[4] = c1; e1_[5] = c2;
#pragma unroll
        for (int i = 0; i < 6; ++i) ehw[i][el] = (_Float16)e1_[i];
    }

    // ---- y-stage: swizzled b32 stores ----
    const int sw0 = lane & 0x38;
    const int sw1 = lane & 8;
#pragma unroll 4
    for (int o = 0; o < 64; o += 2) {
        const float s0a = bn0s[o], b0a = bn0b[o];
        const float s0b = bn0s[o + 1], b0b = bn0b[o + 1];
        const float* wra = w0 + o * 6;
        const float* wrb = wra + 6;
        float ya = wra[0] * e0[0] + wra[1] * e0[1] + wra[2] * e0[2] +
                   wra[3] * e0[3] + wra[4] * e0[4] + wra[5] * e0[5];
        ya = ya * s0a + b0a; ya = fmaxf(ya, NEGSLOPE * ya);
        float yb = wrb[0] * e0[0] + wrb[1] * e0[1] + wrb[2] * e0[2] +
                   wrb[3] * e0[3] + wrb[4] * e0[4] + wrb[5] * e0[5];
        yb = yb * s0b + b0b; yb = fmaxf(yb, NEGSLOPE * yb);
        *(half2v*)&yw[lane * YSTRIDE + (o ^ sw0)] =
            (half2v){(_Float16)ya, (_Float16)yb};
        if (lane < 16) {
            float yc = wra[0] * e1_[0] + wra[1] * e1_[1] + wra[2] * e1_[2] +
                       wra[3] * e1_[3] + wra[4] * e1_[4] + wra[5] * e1_[5];
            yc = yc * s0a + b0a; yc = fmaxf(yc, NEGSLOPE * yc);
            float yd = wrb[0] * e1_[0] + wrb[1] * e1_[1] + wrb[2] * e1_[2] +
                       wrb[3] * e1_[3] + wrb[4] * e1_[4] + wrb[5] * e1_[5];
            yd = yd * s0b + b0b; yd = fmaxf(yd, NEGSLOPE * yd);
            *(half2v*)&yw[(64 + lane) * YSTRIDE + (o ^ sw1)] =
                (half2v){(_Float16)yc, (_Float16)yd};
        }
    }

    __syncthreads();

    const half8* w1g8 = (const half8*)w1g;

    f32x4 acc[5][4];
#pragma unroll
    for (int mm = 0; mm < 5; ++mm)
#pragma unroll
        for (int t4 = 0; t4 < 4; ++t4) acc[mm][t4] = (f32x4){0.f, 0.f, 0.f, 0.f};

#pragma unroll 1
    for (int i6 = 0; i6 < 6; ++i6) {
        _Float16 es[5];
#pragma unroll
        for (int mm = 0; mm < 5; ++mm) es[mm] = ehw[i6][16 * mm + c];
#pragma unroll
        for (int ks2 = 0; ks2 < 2; ++ks2) {
            const int ks = 2 * i6 + ks2;
            half8 B[4];
#pragma unroll
            for (int t4 = 0; t4 < 4; ++t4)
                B[t4] = w1g8[(ks * 4 + t4) * 64 + lane];
#pragma unroll
            for (int mm = 0; mm < 5; ++mm) {
                const int rrow = 16 * mm + c;
                const half8 Af = *(const half8*)&yw[rrow * YSTRIDE +
                                                    ((32 * ks2 + 8 * q) ^ (rrow & 0x38))];
                const half8 An = Af * es[mm];
#pragma unroll
                for (int t4 = 0; t4 < 4; ++t4)
                    acc[mm][t4] = __builtin_amdgcn_mfma_f32_16x16x32_f16(
                        An, B[t4], acc[mm][t4], 0, 0, 0);
            }
        }
    }

    float bs1[4], bb1[4];
#pragma unroll
    for (int t4 = 0; t4 < 4; ++t4) {
        bs1[t4] = bn1s[16 * t4 + c];
        bb1[t4] = bn1b[16 * t4 + c];
    }

    float x1[4][4];
#pragma unroll
    for (int r = 0; r < 4; ++r)
#pragma unroll
        for (int t4 = 0; t4 < 4; ++t4) {
            float v = NINF;
#pragma unroll
            for (int mm = 0; mm < 5; ++mm) {
                float w = acc[mm][t4][r] * bs1[t4] + bb1[t4];
                w = fmaxf(w, NEGSLOPE * w);
                v = fmaxf(v, w);
            }
            v = fmaxf(v, __shfl_xor(v, 16, 64));
            v = fmaxf(v, __shfl_xor(v, 32, 64));
            x1[r][t4] = v;
        }

    float wcv[3][4];
#pragma unroll
    for (int co = 0; co < 3; ++co)
#pragma unroll
        for (int t4 = 0; t4 < 4; ++t4) wcv[co][t4] = wc[co * 64 + 16 * t4 + c];

    float part[4][3];
#pragma unroll
    for (int r = 0; r < 4; ++r)
#pragma unroll
        for (int co = 0; co < 3; ++co) {
            float s = x1[r][0] * wcv[co][0] + x1[r][1] * wcv[co][1] +
                      x1[r][2] * wcv[co][2] + x1[r][3] * wcv[co][3];
#pragma unroll
            for (int d = 1; d < 16; d <<= 1) s += __shfl_xor(s, d, 64);
            part[r][co] = s;
        }

    if (c == 0 && q < 3) {
        const float sc = bncs[q], bc = bncb[q];
#pragma unroll
        for (int r = 0; r < 4; ++r) {
            float z = part[r][q] * sc + bc;
            z = fmaxf(z, NEGSLOPE * z);
            out[(b * 3 + q) * 2048 + P0 + r] = z;
        }
    }
}

// ---------------------------------------------------------------------------
extern "C" void kernel_launch(void* const* d_in, const int* in_sizes, int n_in,
                              void* d_out, int out_size, void* d_ws, size_t ws_size,
                              hipStream_t stream) {
    const float* x    = (const float*)d_in[0];
    const float* W0   = (const float*)d_in[1];
    const float* bn0s = (const float*)d_in[2];
    const float* bn0b = (const float*)d_in[3];
    const float* W1   = (const float*)d_in[4];
    const float* bn1s = (const float*)d_in[5];
    const float* bn1b = (const float*)d_in[6];
    const float* Wc   = (const float*)d_in[7];
    const float* bncs = (const float*)d_in[8];
    const float* bncb = (const float*)d_in[9];

    _Float16* w1g = (_Float16*)d_ws;             // 24576 f16 = 48 KiB
    int* idx = (int*)((char*)d_ws + 65536);      // 16384*20 ints = 1.25 MiB

    topk_kernel<<<2056, 256, 0, stream>>>(x, idx, W1, w1g);
    mlp_mfma<<<2048, 128, 0, stream>>>(x, idx, W0, bn0s, bn0b, w1g,
                                       bn1s, bn1b, Wc, bncs, bncb,
                                       (float*)d_out);
}

// Round 10
// 151.864 us; speedup vs baseline: 1.1112x; 1.1112x over previous
//
#include <hip/hip_runtime.h>

#define NEGSLOPE 0.2f
#define NINF (-3.4e38f)

typedef _Float16 half8 __attribute__((ext_vector_type(8)));
typedef float f32x4 __attribute__((ext_vector_type(4)));
typedef unsigned long long u64;

#define YSTRIDE 72  // f16 units; row stride 144 B (16B-aligned for b128)

__device__ __forceinline__ half8 h8zero() {
    half8 z;
#pragma unroll
    for (int i = 0; i < 8; ++i) z[i] = (_Float16)0.f;
    return z;
}

// ---------------------------------------------------------------------------
// topk v8 (revert to best-known): one wave per row; key = bits(d^2), MIN-
// select of (key<<32)|j (tie = smaller j, matches jax). Per-lane top-2,
// self-skip, zmask + rare refill. Wave argmin = 6-step DPP min chain
// (old=-1 neutral) -> lane 63 + ballot/ffs/readlane decode (R7-proven).
// Blocks >= 4096: prep path -- w1g (W1 -> f16 B-frag order), w0f (W0 rows
// as zero-padded half8), xt (x -> point-major f32x4).
// ---------------------------------------------------------------------------
template <int CTRL>
__device__ __forceinline__ unsigned dpp_movm(unsigned v) {
    return (unsigned)__builtin_amdgcn_update_dpp(-1, (int)v, CTRL, 0xF, 0xF, false);
}

__global__ __launch_bounds__(256) void topk_kernel(
    const float* __restrict__ x, int* __restrict__ idx_out,
    const float* __restrict__ w1, _Float16* __restrict__ w1g,
    const float* __restrict__ w0, _Float16* __restrict__ w0f,
    f32x4* __restrict__ xt) {
    if (blockIdx.x >= 4096) {
        const int pid = blockIdx.x - 4096;   // 0..7
        // ---- w1g: 24576 f16 ----
        int tid = pid * 256 + threadIdx.x;
#pragma unroll
        for (int it = 0; it < 12; ++it, tid += 2048) {
            int j = tid & 7;
            int L = (tid >> 3) & 63;
            int r = tid >> 9;          // r = ks*4 + t4
            int t4 = r & 3;
            int ks = r >> 2;
            int q = L >> 4, c = L & 15;
            int i = ks >> 1;
            int o = 32 * (ks & 1) + 8 * q + j;
            int u = 16 * t4 + c;
            w1g[tid] = (_Float16)w1[(u * 6 + i) * 64 + o];
        }
        // ---- w0f: 64 rows x 8 (j<6 = W0[row][j], else 0) ----
        if (pid == 0) {
#pragma unroll
            for (int s = 0; s < 2; ++s) {
                int t2 = threadIdx.x * 2 + s;
                int r8 = t2 >> 3, j = t2 & 7;
                w0f[t2] = (j < 6) ? (_Float16)w0[r8 * 6 + j] : (_Float16)0.f;
            }
        }
        // ---- xt: 16384 points, (x,y,z,0) ----
        int base = pid * 2048;
#pragma unroll
        for (int it = 0; it < 8; ++it) {
            int i = base + it * 256 + threadIdx.x;
            int bb = i >> 11, n = i & 2047;
            const float* xbp = x + bb * 6144;
            xt[i] = (f32x4){xbp[n], xbp[2048 + n], xbp[4096 + n], 0.f};
        }
        return;
    }

    const int wave = threadIdx.x >> 6;
    const int lane = threadIdx.x & 63;
    const int row = blockIdx.x * 4 + wave;
    const int b = row >> 11;
    const int n = row & 2047;
    const float* xb = x + b * 6144;
    const float xn0 = xb[n];
    const float xn1 = xb[2048 + n];
    const float xn2 = xb[4096 + n];

    unsigned skh[32];                 // key per candidate t (j = t*64+lane)
    u64 g1 = ~0ull, g2 = ~0ull;      // per-lane top-2 (min), (key<<32)|j

#pragma unroll
    for (int t = 0; t < 32; ++t) {
        const int j = t * 64 + lane;
        const float dx = xb[j] - xn0;
        const float dy = xb[2048 + j] - xn1;
        const float dz = xb[4096 + j] - xn2;
        const float d = dx * dx + dy * dy + dz * dz;
        const unsigned s = __float_as_uint(d);
        skh[t] = s;
        const u64 cand = ((u64)s << 32) | (unsigned)j;
        const bool lt = cand < g1;
        const u64 dem = lt ? g1 : cand;
        g1 = lt ? cand : g1;
        if (dem < g2) g2 = dem;
    }

    const int out_base = row * 20;

    // self-skip: d(self)=0 -> key 0 is the strict global min.
    if (lane == 0) idx_out[out_base] = n;
    const bool selfLane = (lane == (n & 63));
    unsigned zmask = selfLane ? (1u << (n >> 6)) : 0u;
    if (selfLane) { g1 = g2; g2 = ~0ull; }

    for (int k = 1; k < 20; ++k) {
        // wave argmin via 6-step DPP min chain; result lands in lane 63
        unsigned m = (unsigned)(g1 >> 32);
        { unsigned o = dpp_movm<0x111>(m); m = o < m ? o : m; }  // row_shr:1
        { unsigned o = dpp_movm<0x112>(m); m = o < m ? o : m; }  // row_shr:2
        { unsigned o = dpp_movm<0x114>(m); m = o < m ? o : m; }  // row_shr:4
        { unsigned o = dpp_movm<0x118>(m); m = o < m ? o : m; }  // row_shr:8
        { unsigned o = dpp_movm<0x142>(m); m = o < m ? o : m; }  // row_bcast:15
        { unsigned o = dpp_movm<0x143>(m); m = o < m ? o : m; }  // row_bcast:31
        const unsigned K = (unsigned)__builtin_amdgcn_readlane((int)m, 63);
        const u64 ball = __ballot((unsigned)(g1 >> 32) == K);
        const int Ls = __ffsll(ball) - 1;
        const int bj = __builtin_amdgcn_readlane((int)(unsigned)g1, Ls);
        if (lane == 0) idx_out[out_base + k] = bj;

        if (k < 19) {
            const bool isL = (lane == Ls);
            zmask |= isL ? (1u << (bj >> 6)) : 0u;
            if (isL) { g1 = g2; g2 = ~0ull; }
            const unsigned h1 = (unsigned)(g1 >> 32);
            // depletion check on winner lane (wave-uniform branch)
            if (__builtin_amdgcn_readlane((int)h1, Ls) == -1) {
                u64 n1 = ~0ull, n2 = ~0ull;
#pragma unroll
                for (int t = 0; t < 32; ++t) {
                    const unsigned sv =
                        ((zmask >> t) & 1u) ? 0xFFFFFFFFu : skh[t];
                    const u64 cc = ((u64)sv << 32) | (unsigned)(t * 64 + lane);
                    const bool lt = cc < n1;
                    const u64 dem = lt ? n1 : cc;
                    n1 = lt ? cc : n1;
                    if (dem < n2) n2 = dem;
                }
                g1 = n1;
                g2 = n2;
            }
        }
    }
}

// ---------------------------------------------------------------------------
// mlp v3: e-stage = one b128 gather per edge (xt), e -> LDS half8.
// y-stage = MFMA (e(80x6) @ W0^T via 20 16x16x32 f16 MFMAs, k>=6 zero) +
// bn0/leaky on C-frags + scatter into XOR-swizzled y tile. No barrier
// (yL/eL are per-wave; in-wave LDS ordering via lgkmcnt). GEMM2 (K=384)
// unchanged/verified.
// ---------------------------------------------------------------------------
__global__ __launch_bounds__(128, 3) void mlp_mfma(
    const f32x4* __restrict__ xt, const int* __restrict__ idx,
    const _Float16* __restrict__ w0f, const float* __restrict__ bn0s,
    const float* __restrict__ bn0b, const _Float16* __restrict__ w1g,
    const float* __restrict__ bn1s, const float* __restrict__ bn1b,
    const float* __restrict__ wc, const float* __restrict__ bncs,
    const float* __restrict__ bncb, float* __restrict__ out) {
    __shared__ __align__(16) _Float16 yL[2][80 * YSTRIDE];
    __shared__ __align__(16) half8 eL[2][80];
    const int wave = threadIdx.x >> 6;
    const int lane = threadIdx.x & 63;
    const int q = lane >> 4, c = lane & 15;
    const int gw = blockIdx.x * 2 + wave;     // 0..4095
    const int b = gw >> 9;                    // 512 waves per batch
    const int P0 = (gw & 511) * 4;
    _Float16* yw = yL[wave];
    half8* ew = eL[wave];
    const f32x4* xtb = xt + (b << 11);

    // ---- e-stage: lane <-> edge (and +64 for lanes<16); 1 gather/edge ----
    {
        const int k = lane >> 2, pt = lane & 3;
        const int n = P0 + pt;
        const int j = idx[(b * 2048 + n) * 20 + k];
        const f32x4 cc = xtb[n];
        const f32x4 nb = xtb[j];
        half8 ev;
        ev[0] = (_Float16)(nb[0] - cc[0]); ev[1] = (_Float16)(nb[1] - cc[1]);
        ev[2] = (_Float16)(nb[2] - cc[2]); ev[3] = (_Float16)cc[0];
        ev[4] = (_Float16)cc[1];           ev[5] = (_Float16)cc[2];
        ev[6] = (_Float16)0.f;             ev[7] = (_Float16)0.f;
        ew[lane] = ev;
    }
    if (lane < 16) {
        const int el = 64 + lane;
        const int k = el >> 2, pt = el & 3;
        const int n = P0 + pt;
        const int j = idx[(b * 2048 + n) * 20 + k];
        const f32x4 cc = xtb[n];
        const f32x4 nb = xtb[j];
        half8 ev;
        ev[0] = (_Float16)(nb[0] - cc[0]); ev[1] = (_Float16)(nb[1] - cc[1]);
        ev[2] = (_Float16)(nb[2] - cc[2]); ev[3] = (_Float16)cc[0];
        ev[4] = (_Float16)cc[1];           ev[5] = (_Float16)cc[2];
        ev[6] = (_Float16)0.f;             ev[7] = (_Float16)0.f;
        ew[el] = ev;
    }

    // ---- y-stage via MFMA: y_raw = e @ W0^T, bn0+leaky, swizzled scatter --
    const half8* w0f8 = (const half8*)w0f;
    const half8 z8 = h8zero();
    half8 B1[4];
    float s0v[4], b0v[4];
#pragma unroll
    for (int nt = 0; nt < 4; ++nt) {
        const half8 v = w0f8[nt * 16 + c];
        B1[nt] = (q == 0) ? v : z8;
        s0v[nt] = bn0s[16 * nt + c];
        b0v[nt] = bn0b[16 * nt + c];
    }
#pragma unroll
    for (int mt = 0; mt < 5; ++mt) {
        const half8 ev = ew[16 * mt + c];
        const half8 Ae = (q == 0) ? ev : z8;
        const int ebase = 16 * mt + 4 * q;
#pragma unroll
        for (int nt = 0; nt < 4; ++nt) {
            f32x4 D = {0.f, 0.f, 0.f, 0.f};
            D = __builtin_amdgcn_mfma_f32_16x16x32_f16(Ae, B1[nt], D, 0, 0, 0);
#pragma unroll
            for (int r = 0; r < 4; ++r) {
                float v = D[r] * s0v[nt] + b0v[nt];
                v = fmaxf(v, NEGSLOPE * v);
                const int edge = ebase + r;
                yw[edge * YSTRIDE + ((16 * nt + c) ^ (edge & 0x38))] =
                    (_Float16)v;
            }
        }
    }

    // ---- GEMM2: K=384, acc chained through MFMA C (verified) ----
    const half8* w1g8 = (const half8*)w1g;

    f32x4 acc[5][4];  // [m][t4], u = 16*t4 + c, edge row = 4q + r
#pragma unroll
    for (int mm = 0; mm < 5; ++mm)
#pragma unroll
        for (int t4 = 0; t4 < 4; ++t4) acc[mm][t4] = (f32x4){0.f, 0.f, 0.f, 0.f};

#pragma unroll 1
    for (int i6 = 0; i6 < 6; ++i6) {
        _Float16 es[5];
#pragma unroll
        for (int mm = 0; mm < 5; ++mm)
            es[mm] = ((const _Float16*)(ew + 16 * mm + c))[i6];
#pragma unroll
        for (int ks2 = 0; ks2 < 2; ++ks2) {
            const int ks = 2 * i6 + ks2;
            half8 B[4];
#pragma unroll
            for (int t4 = 0; t4 < 4; ++t4)
                B[t4] = w1g8[(ks * 4 + t4) * 64 + lane];
#pragma unroll
            for (int mm = 0; mm < 5; ++mm) {
                const int rrow = 16 * mm + c;
                const half8 Af = *(const half8*)&yw[rrow * YSTRIDE +
                                                    ((32 * ks2 + 8 * q) ^ (rrow & 0x38))];
                const half8 An = Af * es[mm];
#pragma unroll
                for (int t4 = 0; t4 < 4; ++t4)
                    acc[mm][t4] = __builtin_amdgcn_mfma_f32_16x16x32_f16(
                        An, B[t4], acc[mm][t4], 0, 0, 0);
            }
        }
    }

    // ---- bn1 + leaky + max over k (k = 4m+q) ----
    float bs1[4], bb1[4];
#pragma unroll
    for (int t4 = 0; t4 < 4; ++t4) {
        bs1[t4] = bn1s[16 * t4 + c];
        bb1[t4] = bn1b[16 * t4 + c];
    }

    float x1[4][4];  // [pt r][t4]
#pragma unroll
    for (int r = 0; r < 4; ++r)
#pragma unroll
        for (int t4 = 0; t4 < 4; ++t4) {
            float v = NINF;
#pragma unroll
            for (int mm = 0; mm < 5; ++mm) {
                float w = acc[mm][t4][r] * bs1[t4] + bb1[t4];
                w = fmaxf(w, NEGSLOPE * w);
                v = fmaxf(v, w);
            }
            v = fmaxf(v, __shfl_xor(v, 16, 64));
            v = fmaxf(v, __shfl_xor(v, 32, 64));
            x1[r][t4] = v;
        }

    // ---- head: z[pt][co] = leaky(bnc(sum_u x1*wc)) ----
    float wcv[3][4];
#pragma unroll
    for (int co = 0; co < 3; ++co)
#pragma unroll
        for (int t4 = 0; t4 < 4; ++t4) wcv[co][t4] = wc[co * 64 + 16 * t4 + c];

    float part[4][3];
#pragma unroll
    for (int r = 0; r < 4; ++r)
#pragma unroll
        for (int co = 0; co < 3; ++co) {
            float s = x1[r][0] * wcv[co][0] + x1[r][1] * wcv[co][1] +
                      x1[r][2] * wcv[co][2] + x1[r][3] * wcv[co][3];
#pragma unroll
            for (int d = 1; d < 16; d <<= 1) s += __shfl_xor(s, d, 64);
            part[r][co] = s;
        }

    if (c == 0 && q < 3) {
        const float sc = bncs[q], bc = bncb[q];
#pragma unroll
        for (int r = 0; r < 4; ++r) {
            float z = part[r][q] * sc + bc;
            z = fmaxf(z, NEGSLOPE * z);
            out[(b * 3 + q) * 2048 + P0 + r] = z;
        }
    }
}

// ---------------------------------------------------------------------------
extern "C" void kernel_launch(void* const* d_in, const int* in_sizes, int n_in,
                              void* d_out, int out_size, void* d_ws, size_t ws_size,
                              hipStream_t stream) {
    const float* x    = (const float*)d_in[0];
    const float* W0   = (const float*)d_in[1];
    const float* bn0s = (const float*)d_in[2];
    const float* bn0b = (const float*)d_in[3];
    const float* W1   = (const float*)d_in[4];
    const float* bn1s = (const float*)d_in[5];
    const float* bn1b = (const float*)d_in[6];
    const float* Wc   = (const float*)d_in[7];
    const float* bncs = (const float*)d_in[8];
    const float* bncb = (const float*)d_in[9];

    _Float16* w1g = (_Float16*)d_ws;                     // 48 KiB @ 0
    _Float16* w0f = (_Float16*)((char*)d_ws + 49152);    // 1 KiB
    f32x4* xt = (f32x4*)((char*)d_ws + 65536);           // 256 KiB
    int* idx = (int*)((char*)d_ws + 327680);             // 1.25 MiB

    topk_kernel<<<4104, 256, 0, stream>>>(x, idx, W1, w1g, W0, w0f, xt);
    mlp_mfma<<<2048, 128, 0, stream>>>(xt, idx, w0f, bn0s, bn0b, w1g,
                                       bn1s, bn1b, Wc, bncs, bncb,
                                       (float*)d_out);
}